// Round 6
// baseline (478.209 us; speedup 1.0000x reference)
//
#include <hip/hip_runtime.h>
#include <math.h>

#define NN 100000
#define NE 1600000
#define CH 128
#define OUTC 16
#define NG 64

#define CBSH 9                      // 512 nodes per coarse bucket
#define NCB 196                     // ceil(NN / 512)
#define CHK 8192                    // edges per passA block
#define MAXB 12288                  // csr staging capacity per bucket (avg 8192)
#define LDA 136                     // LDS A-tile row stride in ushorts (272 B = 17*16)
#define AGB (NN / 16)               // 6250 agg blocks

typedef __attribute__((ext_vector_type(8))) short bf16x8;
typedef __attribute__((ext_vector_type(4))) float f32x4;

__device__ __forceinline__ unsigned short f2bf(float f) {
    union { float f; unsigned u; } v; v.f = f;
    unsigned r = v.u + 0x7FFF + ((v.u >> 16) & 1);   // RNE
    return (unsigned short)(r >> 16);
}
__device__ __forceinline__ float bflo(unsigned u) {
    union { unsigned u; float f; } v; v.u = u << 16; return v.f;
}
__device__ __forceinline__ float bfhi(unsigned u) {
    union { unsigned u; float f; } v; v.u = u & 0xffff0000u; return v.f;
}

// ---------------- prep: cast W1/W2 -> WT bf16, build gptr, zero all accumulators ----
__global__ void k_prep(const float* __restrict__ W1, const float* __restrict__ W2,
                       unsigned short* __restrict__ wt1, unsigned short* __restrict__ wt2,
                       const int* __restrict__ batch, int* __restrict__ gptr,
                       int* __restrict__ bcnt, int* __restrict__ gfill,
                       float* __restrict__ pooled, int* __restrict__ done) {
    int i = blockIdx.x * 256 + threadIdx.x;
    if (i < CH * CH) {
        int k = i >> 7, n = i & 127;
        wt1[n * CH + k] = f2bf(W1[i]);
    } else if (i < 2 * CH * CH) {
        int j = i - CH * CH;
        int k = j >> 7, n = j & 127;
        wt2[n * CH + k] = f2bf(W2[j]);
    }
    if (i < NCB) { bcnt[i] = 0; gfill[i] = 0; }
    if (i < NG * CH) pooled[i] = 0.f;
    if (i == 0) *done = 0;
    if (i < NN) {
        int b = batch[i];
        int prev = (i == 0) ? -1 : batch[i - 1];
        for (int g = prev + 1; g <= b; g++) gptr[g] = i;
        if (i == NN - 1) {
            for (int g = b + 1; g <= NG; g++) gptr[g] = NN;
        }
    }
}

// ---------------- coarse histogram: 196 buckets of 512 nodes ----------------
__global__ __launch_bounds__(1024) void k_hist(const int* __restrict__ dst, int* __restrict__ bcnt) {
    __shared__ int h[NCB];
    int t = threadIdx.x;
    if (t < NCB) h[t] = 0;
    __syncthreads();
    int base = blockIdx.x * CHK;
#pragma unroll
    for (int i = 0; i < 8; i++) {
        int e = base + i * 1024 + t;
        if (e < NE) atomicAdd(&h[dst[e] >> CBSH], 1);
    }
    __syncthreads();
    if (t < NCB && h[t]) atomicAdd(&bcnt[t], h[t]);
}

// ---------------- pass A: counting-sort edges into coarse buckets ----------------
__global__ __launch_bounds__(1024) void k_passA(const int* __restrict__ src, const int* __restrict__ dst,
                        const int* __restrict__ bcnt, int* __restrict__ gfill,
                        unsigned* __restrict__ ebuf) {
    __shared__ unsigned lbuf[CHK];
    __shared__ unsigned char lbyte[CHK];
    __shared__ int hcnt[NCB];
    __shared__ int hbase[256];   // inclusive scan of hcnt
    __shared__ int eb[256];      // inclusive scan of bcnt
    __shared__ int goff[NCB];
    int t = threadIdx.x;
    if (t < NCB) hcnt[t] = 0;
    if (t < 256) eb[t] = (t < NCB) ? bcnt[t] : 0;
    __syncthreads();
    int base = blockIdx.x * CHK;
    int cb[8], slot[8]; unsigned pk[8];
#pragma unroll
    for (int i = 0; i < 8; i++) {
        int e = base + i * 1024 + t;
        cb[i] = -1;
        if (e < NE) {
            int d = dst[e], s = src[e];
            cb[i] = d >> CBSH;
            pk[i] = ((unsigned)s << CBSH) | (unsigned)(d & 511);
            slot[i] = atomicAdd(&hcnt[cb[i]], 1);
        }
    }
    __syncthreads();
    if (t < 256) hbase[t] = (t < NCB) ? hcnt[t] : 0;
    __syncthreads();
    for (int off = 1; off < 256; off <<= 1) {
        int v1 = 0, v2 = 0;
        if (t < 256 && t >= off) { v1 = hbase[t - off]; v2 = eb[t - off]; }
        __syncthreads();
        if (t < 256 && t >= off) { hbase[t] += v1; eb[t] += v2; }
        __syncthreads();
    }
    if (t < NCB) {
        int c = hcnt[t];
        int g = c ? atomicAdd(&gfill[t], c) : 0;
        int ebase_t = t ? eb[t - 1] : 0;
        goff[t] = ebase_t + g - (hbase[t] - c);
    }
    __syncthreads();
#pragma unroll
    for (int i = 0; i < 8; i++) {
        if (cb[i] >= 0) {
            int pos = hbase[cb[i]] - hcnt[cb[i]] + slot[i];
            lbuf[pos] = pk[i];
            lbyte[pos] = (unsigned char)cb[i];
        }
    }
    __syncthreads();
    int total = min(NE - base, CHK);
    for (int p = t; p < total; p += 1024) {
        unsigned v = lbuf[p];
        int b = lbyte[p];
        ebuf[goff[b] + p] = v;
    }
}

// ---------------- pass B: per-bucket node sort -> csr/degi/rowst/dis ----------------
__global__ __launch_bounds__(1024) void k_passB(const unsigned* __restrict__ ebuf, const int* __restrict__ bcnt,
                        int* __restrict__ degi, int* __restrict__ rowst,
                        float* __restrict__ dis, int* __restrict__ csr) {
    __shared__ int cnt[512];
    __shared__ int nbase[512];
    __shared__ int fill[512];
    __shared__ int stage[MAXB];
    __shared__ int eb[256];      // inclusive scan of bcnt
    int t = threadIdx.x;
    int cb = blockIdx.x;
    int nb0 = cb << CBSH;
    int ncnt = min(512, NN - nb0);
    if (t < 512) { cnt[t] = 0; fill[t] = 0; }
    if (t < 256) eb[t] = (t < NCB) ? bcnt[t] : 0;
    __syncthreads();
    for (int off = 1; off < 256; off <<= 1) {
        int v = 0;
        if (t < 256 && t >= off) v = eb[t - off];
        __syncthreads();
        if (t < 256 && t >= off) eb[t] += v;
        __syncthreads();
    }
    int e0 = cb ? eb[cb - 1] : 0;
    int e1 = eb[cb];
    for (int e = e0 + t; e < e1; e += 1024)
        atomicAdd(&cnt[ebuf[e] & 511], 1);
    __syncthreads();
    if (t < 512) nbase[t] = cnt[t];
    __syncthreads();
    for (int off = 1; off < 512; off <<= 1) {
        int v = 0;
        if (t < 512 && t >= off) v = nbase[t - off];
        __syncthreads();
        if (t < 512) nbase[t] += v;
        __syncthreads();
    }
    for (int e = e0 + t; e < e1; e += 1024) {
        unsigned v = ebuf[e];
        int local = v & 511;
        int s = atomicAdd(&fill[local], 1);
        stage[nbase[local] - cnt[local] + s] = (int)(v >> CBSH);
    }
    __syncthreads();
    int total = e1 - e0;
    for (int p = t; p < total; p += 1024) csr[e0 + p] = stage[p];
    if (t < ncnt) {
        int c = cnt[t];
        degi[nb0 + t] = c;
        rowst[nb0 + t] = e0 + nbase[t] - c;
        dis[nb0 + t] = rsqrtf((float)c + 1.0f);
    }
}

// ---------------- MFMA GEMM (layer 1): out = bf16((x @ W1) * dis), LDS-staged A ----
__launch_bounds__(256, 2)
__global__ void k_gemm1(const float* __restrict__ Av,
                        const unsigned short* __restrict__ WT,
                        const float* __restrict__ dis,
                        unsigned short* __restrict__ out) {
    __shared__ unsigned short As[128 * LDA];   // 34816 B
    int tid = threadIdx.x;
    int wave = tid >> 6, lane = tid & 63;
    int quad = lane >> 4, l16 = lane & 15;

    int rbase = blockIdx.x * 128;
    int nval = min(128, NN - rbase);

    const float* X = Av + (size_t)rbase * CH;
#pragma unroll
    for (int i = 0; i < 16; i++) {
        int off = i * 1024 + tid * 4;        // float index in tile
        int row = off >> 7, col = off & 127;
        if (row < nval) {
            float4 f = *(const float4*)(X + (size_t)row * CH + col);
            uint2 pk;
            pk.x = (unsigned)f2bf(f.x) | ((unsigned)f2bf(f.y) << 16);
            pk.y = (unsigned)f2bf(f.z) | ((unsigned)f2bf(f.w) << 16);
            *(uint2*)(&As[row * LDA + col]) = pk;
        }
    }
    __syncthreads();

    int wrow = wave * 32;
    bf16x8 af[2][4];
#pragma unroll
    for (int s = 0; s < 2; s++)
#pragma unroll
        for (int ks = 0; ks < 4; ks++)
            af[s][ks] = *(const bf16x8*)(&As[(wrow + s * 16 + l16) * LDA + ks * 32 + quad * 8]);

    f32x4 acc[2][8];
#pragma unroll
    for (int s = 0; s < 2; s++)
#pragma unroll
        for (int t = 0; t < 8; t++) acc[s][t] = (f32x4){0.f, 0.f, 0.f, 0.f};

#pragma unroll
    for (int t = 0; t < 8; t++) {
        const unsigned short* wcol = WT + (size_t)(t * 16 + l16) * CH + quad * 8;
        bf16x8 b0 = *(const bf16x8*)(wcol);
        bf16x8 b1 = *(const bf16x8*)(wcol + 32);
        bf16x8 b2 = *(const bf16x8*)(wcol + 64);
        bf16x8 b3 = *(const bf16x8*)(wcol + 96);
#pragma unroll
        for (int s = 0; s < 2; s++) {
            acc[s][t] = __builtin_amdgcn_mfma_f32_16x16x32_bf16(b0, af[s][0], acc[s][t], 0, 0, 0);
            acc[s][t] = __builtin_amdgcn_mfma_f32_16x16x32_bf16(b1, af[s][1], acc[s][t], 0, 0, 0);
            acc[s][t] = __builtin_amdgcn_mfma_f32_16x16x32_bf16(b2, af[s][2], acc[s][t], 0, 0, 0);
            acc[s][t] = __builtin_amdgcn_mfma_f32_16x16x32_bf16(b3, af[s][3], acc[s][t], 0, 0, 0);
        }
    }

    // Swapped D layout: node = rbase + wave*32 + s*16 + l16, channel = t*16 + quad*4 + r
#pragma unroll
    for (int s = 0; s < 2; s++) {
        int node = rbase + wrow + s * 16 + l16;
        int cl = (node < NN) ? node : NN - 1;
        float d = dis[cl];
        if (node < NN) {
#pragma unroll
            for (int t = 0; t < 8; t++) {
                unsigned lo = ((unsigned)f2bf(acc[s][t][1] * d) << 16) | (unsigned)f2bf(acc[s][t][0] * d);
                unsigned hi = ((unsigned)f2bf(acc[s][t][3] * d) << 16) | (unsigned)f2bf(acc[s][t][2] * d);
                uint2 pk; pk.x = lo; pk.y = hi;
                *(uint2*)(out + (size_t)node * CH + t * 16 + quad * 4) = pk;
            }
        }
    }
}

// ---------------- FUSED agg(layer1) + gemm(layer2) ----------------
// Gather phase is the proven k_agg (59.7 us floor) verbatim. The block's 16
// relu'd bf16 rows land in LDS (272-B padded stride -> 2-way bank alias, free);
// each of 4 waves then computes 2 output-channel tiles of (h @ W2)*dis with the
// operand-swapped mfma and stores ht2 directly. Deletes the gemm2 dispatch and
// bufB's 25.6 MB write + 25.6 MB re-read.
__global__ __launch_bounds__(256) void k_agg_gemm(const unsigned short* __restrict__ ht,
                      const int* __restrict__ rowst,
                      const int* __restrict__ degi, const int* __restrict__ csr,
                      const float* __restrict__ dis, const float* __restrict__ bias,
                      const unsigned short* __restrict__ WT,
                      unsigned short* __restrict__ out) {
    __shared__ unsigned short As[16 * LDA];
    int t = threadIdx.x;
    int grp = t >> 4;            // node group within block
    int q = t & 15;              // 16-B chunk within row
    int n0 = blockIdx.x * 16;
    int n = n0 + grp;
    const uint4* base = (const uint4*)ht;

    uint4 sv = base[(size_t)n * 16 + q];
    float a[8];
    a[0] = bflo(sv.x); a[1] = bfhi(sv.x);
    a[2] = bflo(sv.y); a[3] = bfhi(sv.y);
    a[4] = bflo(sv.z); a[5] = bfhi(sv.z);
    a[6] = bflo(sv.w); a[7] = bfhi(sv.w);

    int start = rowst[n];
    int c = degi[n];
    int nb = c & ~7;
    int j = 0;
    for (; j < nb; j += 8) {
        int idx[8];
#pragma unroll
        for (int u = 0; u < 8; u++) idx[u] = csr[start + j + u];
        uint4 v[8];
#pragma unroll
        for (int u = 0; u < 8; u++) v[u] = base[(size_t)idx[u] * 16 + q];
#pragma unroll
        for (int u = 0; u < 8; u++) {
            a[0] += bflo(v[u].x); a[1] += bfhi(v[u].x);
            a[2] += bflo(v[u].y); a[3] += bfhi(v[u].y);
            a[4] += bflo(v[u].z); a[5] += bfhi(v[u].z);
            a[6] += bflo(v[u].w); a[7] += bfhi(v[u].w);
        }
    }
    if (j < c) {
        int idx[8];
#pragma unroll
        for (int u = 0; u < 8; u++) { int e = j + u; idx[u] = csr[start + (e < c ? e : c - 1)]; }
        uint4 v[8];
#pragma unroll
        for (int u = 0; u < 8; u++) v[u] = base[(size_t)idx[u] * 16 + q];
#pragma unroll
        for (int u = 0; u < 8; u++) {
            if (j + u < c) {
                a[0] += bflo(v[u].x); a[1] += bfhi(v[u].x);
                a[2] += bflo(v[u].y); a[3] += bfhi(v[u].y);
                a[4] += bflo(v[u].z); a[5] += bfhi(v[u].z);
                a[6] += bflo(v[u].w); a[7] += bfhi(v[u].w);
            }
        }
    }

    float d = dis[n];
    const float4* bp = (const float4*)bias;
    float4 b0 = bp[q * 2], b1 = bp[q * 2 + 1];
    uint4 o;
    {
        float ox = fmaxf(fmaf(d, a[0], b0.x), 0.f), oy = fmaxf(fmaf(d, a[1], b0.y), 0.f);
        o.x = ((unsigned)f2bf(oy) << 16) | (unsigned)f2bf(ox);
        ox = fmaxf(fmaf(d, a[2], b0.z), 0.f); oy = fmaxf(fmaf(d, a[3], b0.w), 0.f);
        o.y = ((unsigned)f2bf(oy) << 16) | (unsigned)f2bf(ox);
        ox = fmaxf(fmaf(d, a[4], b1.x), 0.f); oy = fmaxf(fmaf(d, a[5], b1.y), 0.f);
        o.z = ((unsigned)f2bf(oy) << 16) | (unsigned)f2bf(ox);
        ox = fmaxf(fmaf(d, a[6], b1.z), 0.f); oy = fmaxf(fmaf(d, a[7], b1.w), 0.f);
        o.w = ((unsigned)f2bf(oy) << 16) | (unsigned)f2bf(ox);
    }
    *(uint4*)(&As[grp * LDA + q * 8]) = o;
    __syncthreads();

    // ---- gemm2 tile: 16 nodes x 128 out-channels, 8 MFMA per wave ----
    int wave = t >> 6, lane = t & 63;
    int l16 = lane & 15, quad = lane >> 4;
    bf16x8 af2[4];
#pragma unroll
    for (int ks = 0; ks < 4; ks++)
        af2[ks] = *(const bf16x8*)(&As[l16 * LDA + ks * 32 + quad * 8]);
    int node = n0 + l16;
    float dd = dis[node];
#pragma unroll
    for (int tt = 0; tt < 2; tt++) {
        int tc = wave * 2 + tt;
        const unsigned short* wcol = WT + (size_t)(tc * 16 + l16) * CH + quad * 8;
        f32x4 acc = (f32x4){0.f, 0.f, 0.f, 0.f};
        acc = __builtin_amdgcn_mfma_f32_16x16x32_bf16(*(const bf16x8*)(wcol),      af2[0], acc, 0, 0, 0);
        acc = __builtin_amdgcn_mfma_f32_16x16x32_bf16(*(const bf16x8*)(wcol + 32), af2[1], acc, 0, 0, 0);
        acc = __builtin_amdgcn_mfma_f32_16x16x32_bf16(*(const bf16x8*)(wcol + 64), af2[2], acc, 0, 0, 0);
        acc = __builtin_amdgcn_mfma_f32_16x16x32_bf16(*(const bf16x8*)(wcol + 96), af2[3], acc, 0, 0, 0);
        unsigned lo = ((unsigned)f2bf(acc[1] * dd) << 16) | (unsigned)f2bf(acc[0] * dd);
        unsigned hi = ((unsigned)f2bf(acc[3] * dd) << 16) | (unsigned)f2bf(acc[2] * dd);
        uint2 pk; pk.x = lo; pk.y = hi;
        *(uint2*)(out + (size_t)node * CH + tc * 16 + quad * 4) = pk;
    }
}

// ---------------- FUSED agg(layer2) + mean-pool + FC (last-block ticket) --------
// Gather identical to proven k_agg; relu rows (f32) reduced per-graph in LDS,
// flushed with ~128 atomics/block (nodes are batch-sorted). No per-node output
// at all: deletes agg2's 25.6 MB write, pool's 25.6 MB read, and 2 dispatches.
__global__ __launch_bounds__(256) void k_agg_pool(const unsigned short* __restrict__ ht,
                      const int* __restrict__ rowst,
                      const int* __restrict__ degi, const int* __restrict__ csr,
                      const float* __restrict__ dis, const float* __restrict__ bias,
                      const int* __restrict__ batch, const int* __restrict__ gptr,
                      float* __restrict__ pooled, int* __restrict__ done,
                      const float* __restrict__ Wfc, const float* __restrict__ bfc,
                      float* __restrict__ out) {
    __shared__ float sm[NG * CH];            // 32 KB; head doubles as part[16][132]
    float (*part)[132] = (float (*)[132])sm;
    int t = threadIdx.x;
    int grp = t >> 4;
    int q = t & 15;
    int n0 = blockIdx.x * 16;
    int n = n0 + grp;
    const uint4* base = (const uint4*)ht;

    uint4 sv = base[(size_t)n * 16 + q];
    float a[8];
    a[0] = bflo(sv.x); a[1] = bfhi(sv.x);
    a[2] = bflo(sv.y); a[3] = bfhi(sv.y);
    a[4] = bflo(sv.z); a[5] = bfhi(sv.z);
    a[6] = bflo(sv.w); a[7] = bfhi(sv.w);

    int start = rowst[n];
    int c = degi[n];
    int nb = c & ~7;
    int j = 0;
    for (; j < nb; j += 8) {
        int idx[8];
#pragma unroll
        for (int u = 0; u < 8; u++) idx[u] = csr[start + j + u];
        uint4 v[8];
#pragma unroll
        for (int u = 0; u < 8; u++) v[u] = base[(size_t)idx[u] * 16 + q];
#pragma unroll
        for (int u = 0; u < 8; u++) {
            a[0] += bflo(v[u].x); a[1] += bfhi(v[u].x);
            a[2] += bflo(v[u].y); a[3] += bfhi(v[u].y);
            a[4] += bflo(v[u].z); a[5] += bfhi(v[u].z);
            a[6] += bflo(v[u].w); a[7] += bfhi(v[u].w);
        }
    }
    if (j < c) {
        int idx[8];
#pragma unroll
        for (int u = 0; u < 8; u++) { int e = j + u; idx[u] = csr[start + (e < c ? e : c - 1)]; }
        uint4 v[8];
#pragma unroll
        for (int u = 0; u < 8; u++) v[u] = base[(size_t)idx[u] * 16 + q];
#pragma unroll
        for (int u = 0; u < 8; u++) {
            if (j + u < c) {
                a[0] += bflo(v[u].x); a[1] += bfhi(v[u].x);
                a[2] += bflo(v[u].y); a[3] += bfhi(v[u].y);
                a[4] += bflo(v[u].z); a[5] += bfhi(v[u].z);
                a[6] += bflo(v[u].w); a[7] += bfhi(v[u].w);
            }
        }
    }

    float d = dis[n];
    const float4* bp = (const float4*)bias;
    float4 b0 = bp[q * 2], b1 = bp[q * 2 + 1];
    float4 r0, r1;
    r0.x = fmaxf(fmaf(d, a[0], b0.x), 0.f); r0.y = fmaxf(fmaf(d, a[1], b0.y), 0.f);
    r0.z = fmaxf(fmaf(d, a[2], b0.z), 0.f); r0.w = fmaxf(fmaf(d, a[3], b0.w), 0.f);
    r1.x = fmaxf(fmaf(d, a[4], b1.x), 0.f); r1.y = fmaxf(fmaf(d, a[5], b1.y), 0.f);
    r1.z = fmaxf(fmaf(d, a[6], b1.z), 0.f); r1.w = fmaxf(fmaf(d, a[7], b1.w), 0.f);
    *(float4*)(&part[grp][q * 8])     = r0;
    *(float4*)(&part[grp][q * 8 + 4]) = r1;
    __syncthreads();

    // per-graph flush: nodes batch-sorted -> usually one graph per block
    if (t < CH) {
        int ch = t;
        float s = 0.f;
        int g = batch[n0];
#pragma unroll
        for (int gg = 0; gg < 16; gg++) {
            int b = batch[n0 + gg];
            if (b != g) { atomicAdd(&pooled[g * CH + ch], s); s = 0.f; g = b; }
            s += part[gg][ch];
        }
        atomicAdd(&pooled[g * CH + ch], s);
    }

    // ---- ticket: last block computes the FC head ----
    __shared__ int lastFlag;
    __syncthreads();
    if (t == 0) {
        __threadfence();
        int r = atomicAdd(done, 1);
        lastFlag = (r == AGB - 1) ? 1 : 0;
    }
    __syncthreads();
    if (!lastFlag) return;
    for (int i = t; i < NG * CH; i += 256) sm[i] = atomicAdd(&pooled[i], 0.0f);
    __syncthreads();
    for (int idx = t; idx < NG * OUTC; idx += 256) {
        int gg = idx >> 4, o = idx & 15;
        float cc = (float)(gptr[gg + 1] - gptr[gg]);
        float inv = 1.0f / fmaxf(cc, 1.0f);
        float acc = 0.f;
        for (int k = 0; k < CH; k++) acc += sm[gg * CH + k] * Wfc[k * OUTC + o];
        out[idx] = fmaf(acc, inv, bfc[o]);
    }
}

extern "C" void kernel_launch(void* const* d_in, const int* in_sizes, int n_in,
                              void* d_out, int out_size, void* d_ws, size_t ws_size,
                              hipStream_t stream) {
    (void)in_sizes; (void)n_in; (void)out_size; (void)ws_size;
    const float* x   = (const float*)d_in[0];
    const float* W1  = (const float*)d_in[1];
    const float* b1  = (const float*)d_in[2];
    const float* W2  = (const float*)d_in[3];
    const float* b2  = (const float*)d_in[4];
    const float* Wfc = (const float*)d_in[5];
    const float* bfc = (const float*)d_in[6];
    const int* ei    = (const int*)d_in[7];
    const int* batch = (const int*)d_in[8];
    const int* esrc = ei;
    const int* edst = ei + NE;
    float* out = (float*)d_out;

    char* w = (char*)d_ws;
    unsigned short* bufA = (unsigned short*)w; w += (size_t)NN * CH * 2;
    unsigned short* bufB = (unsigned short*)w; w += (size_t)NN * CH * 2;
    unsigned short* wt1  = (unsigned short*)w; w += (size_t)CH * CH * 2;
    unsigned short* wt2  = (unsigned short*)w; w += (size_t)CH * CH * 2;
    unsigned* ebuf = (unsigned*)w; w += (size_t)NE * 4;
    int* csr    = (int*)w;    w += (size_t)NE * 4;
    int* degi   = (int*)w;    w += (size_t)NN * 4;
    int* rowst  = (int*)w;    w += (size_t)NN * 4;
    float* dis  = (float*)w;  w += (size_t)NN * 4;
    int* bcnt   = (int*)w;    w += NCB * 4;
    int* gfill  = (int*)w;    w += NCB * 4;
    int* gptr   = (int*)w;    w += (NG + 1) * 4;
    float* pooled = (float*)w; w += (size_t)NG * CH * 4;
    int* done   = (int*)w;    w += 4;

    const int histBlocks = (NE + CHK - 1) / CHK;   // 196
    const int gemmBlocks = (NN + 127) / 128;       // 782

    k_prep<<<(NN + 255) / 256, 256, 0, stream>>>(W1, W2, wt1, wt2, batch, gptr, bcnt, gfill, pooled, done);
    k_hist<<<histBlocks, 1024, 0, stream>>>(edst, bcnt);
    k_passA<<<histBlocks, 1024, 0, stream>>>(esrc, edst, bcnt, gfill, ebuf);
    k_passB<<<NCB, 1024, 0, stream>>>(ebuf, bcnt, degi, rowst, dis, csr);

    // layer 1 GEMM (fp32 input, fused cast)
    k_gemm1<<<gemmBlocks, 256, 0, stream>>>(x, wt1, dis, bufA);
    // fused: agg(layer1) + gemm(layer2)
    k_agg_gemm<<<AGB, 256, 0, stream>>>(bufA, rowst, degi, csr, dis, b1, wt2, bufB);
    // fused: agg(layer2) + mean-pool + FC
    k_agg_pool<<<AGB, 256, 0, stream>>>(bufB, rowst, degi, csr, dis, b2, batch, gptr,
                                        pooled, done, Wfc, bfc, out);
}

// Round 7
// 313.726 us; speedup vs baseline: 1.5243x; 1.5243x over previous
//
#include <hip/hip_runtime.h>
#include <math.h>

#define NN 100000
#define NE 1600000
#define CH 128
#define OUTC 16
#define NG 64

#define CBSH 9                      // 512 nodes per coarse bucket
#define NCB 196                     // ceil(NN / 512)
#define CHK 8192                    // edges per passA block
#define MAXB 12288                  // csr staging capacity per bucket (avg 8192)
#define PS 8                        // pool splits per graph
#define LDA 136                     // LDS W-tile row stride in ushorts (272 B = 17*16)

#define GEMMB 782                   // gemm1 blocks in fused0
#define HISTB 196                   // hist blocks in fused0
#define PREPB 391                   // prep blocks in fused0

typedef __attribute__((ext_vector_type(8))) short bf16x8;
typedef __attribute__((ext_vector_type(4))) float f32x4;

__device__ __forceinline__ unsigned short f2bf(float f) {
    union { float f; unsigned u; } v; v.f = f;
    unsigned r = v.u + 0x7FFF + ((v.u >> 16) & 1);   // RNE
    return (unsigned short)(r >> 16);
}
__device__ __forceinline__ float bflo(unsigned u) {
    union { unsigned u; float f; } v; v.u = u << 16; return v.f;
}
__device__ __forceinline__ float bfhi(unsigned u) {
    union { unsigned u; float f; } v; v.u = u & 0xffff0000u; return v.f;
}

// ---------------- fused0: gemm1(unscaled, self-staged W1) | hist | prep ----------
// The three jobs are independent: gemm1 reads x/W1 -> bufA; hist reads edst ->
// hpart (non-atomic per-block histograms, no pre-zero needed); prep casts W2,
// builds gptr, zeroes gfill/pooled. No cross-branch data flow.
__launch_bounds__(256, 2)
__global__ void k_fused0(const float* __restrict__ x, const float* __restrict__ W1,
                         const float* __restrict__ W2,
                         unsigned short* __restrict__ wt2,
                         const int* __restrict__ batch, int* __restrict__ gptr,
                         int* __restrict__ gfill, float* __restrict__ pooled,
                         const int* __restrict__ edst, int* __restrict__ hpart,
                         unsigned short* __restrict__ bufA) {
    __shared__ unsigned short wlds[128 * LDA];   // 34816 B (gemm1); aliased by hist
    int b = blockIdx.x;
    int t = threadIdx.x;

    if (b < GEMMB) {
        // ---- gemm1: out = bf16(x @ W1)  (UNSCALED; agg1 applies dis weights) ----
        // stage W1^T bf16 into LDS (own copy -> no dependency on prep)
#pragma unroll
        for (int it = 0; it < 64; it++) {
            int i = it * 256 + t;                 // i = k*128 + n
            int k = i >> 7, n = i & 127;
            wlds[n * LDA + k] = f2bf(W1[i]);
        }
        __syncthreads();

        int wave = t >> 6, lane = t & 63;
        int quad = lane >> 4, l16 = lane & 15;
        int rbase = b * 128 + wave * 32;

        bf16x8 af[2][4];
#pragma unroll
        for (int s = 0; s < 2; s++) {
            int row = rbase + s * 16 + l16;
            if (row >= NN) row = NN - 1;
            const float* arow = x + (size_t)row * CH + quad * 8;
#pragma unroll
            for (int ks = 0; ks < 4; ks++) {
                float4 lo = *(const float4*)(arow + ks * 32);
                float4 hi = *(const float4*)(arow + ks * 32 + 4);
                union { bf16x8 v; unsigned short u[8]; } tmp;
                tmp.u[0] = f2bf(lo.x); tmp.u[1] = f2bf(lo.y);
                tmp.u[2] = f2bf(lo.z); tmp.u[3] = f2bf(lo.w);
                tmp.u[4] = f2bf(hi.x); tmp.u[5] = f2bf(hi.y);
                tmp.u[6] = f2bf(hi.z); tmp.u[7] = f2bf(hi.w);
                af[s][ks] = tmp.v;
            }
        }

        f32x4 acc[2][8];
#pragma unroll
        for (int s = 0; s < 2; s++)
#pragma unroll
            for (int tt = 0; tt < 8; tt++) acc[s][tt] = (f32x4){0.f, 0.f, 0.f, 0.f};

#pragma unroll
        for (int tt = 0; tt < 8; tt++) {
            const unsigned short* wcol = &wlds[(tt * 16 + l16) * LDA + quad * 8];
            bf16x8 b0 = *(const bf16x8*)(wcol);
            bf16x8 b1 = *(const bf16x8*)(wcol + 32);
            bf16x8 b2 = *(const bf16x8*)(wcol + 64);
            bf16x8 b3 = *(const bf16x8*)(wcol + 96);
#pragma unroll
            for (int s = 0; s < 2; s++) {
                acc[s][tt] = __builtin_amdgcn_mfma_f32_16x16x32_bf16(af[s][0], b0, acc[s][tt], 0, 0, 0);
                acc[s][tt] = __builtin_amdgcn_mfma_f32_16x16x32_bf16(af[s][1], b1, acc[s][tt], 0, 0, 0);
                acc[s][tt] = __builtin_amdgcn_mfma_f32_16x16x32_bf16(af[s][2], b2, acc[s][tt], 0, 0, 0);
                acc[s][tt] = __builtin_amdgcn_mfma_f32_16x16x32_bf16(af[s][3], b3, acc[s][tt], 0, 0, 0);
            }
        }

        // D layout per 16x16 tile: row = quad*4 + r, col = l16
#pragma unroll
        for (int s = 0; s < 2; s++) {
#pragma unroll
            for (int r = 0; r < 4; r++) {
                int orow = rbase + s * 16 + quad * 4 + r;
                if (orow < NN) {
#pragma unroll
                    for (int tt = 0; tt < 8; tt++)
                        bufA[(size_t)orow * CH + tt * 16 + l16] = f2bf(acc[s][tt][r]);
                }
            }
        }
    } else if (b < GEMMB + HISTB) {
        // ---- hist: per-block coarse histogram, non-atomic output ----
        int* h = (int*)wlds;
        if (t < NCB) h[t] = 0;
        __syncthreads();
        int hb = b - GEMMB;
        int base = hb * CHK;
#pragma unroll
        for (int i = 0; i < 32; i++) {
            int e = base + i * 256 + t;
            if (e < NE) atomicAdd(&h[edst[e] >> CBSH], 1);
        }
        __syncthreads();
        if (t < NCB) hpart[hb * NCB + t] = h[t];
    } else {
        // ---- prep: cast W2 -> wt2, build gptr, zero gfill/pooled ----
        int i = (b - GEMMB - HISTB) * 256 + t;
        if (i < CH * CH) {
            int k = i >> 7, n = i & 127;
            wt2[n * CH + k] = f2bf(W2[i]);
        }
        if (i < NCB) gfill[i] = 0;
        if (i < NG * CH) pooled[i] = 0.f;
        if (i < NN) {
            int bb = batch[i];
            int prev = (i == 0) ? -1 : batch[i - 1];
            for (int g = prev + 1; g <= bb; g++) gptr[g] = i;
            if (i == NN - 1) {
                for (int g = bb + 1; g <= NG; g++) gptr[g] = NN;
            }
        }
    }
}

// ---------------- bscan: reduce hpart columns + inclusive scan -> ebase ----------
__global__ __launch_bounds__(256) void k_bscan(const int* __restrict__ hpart,
                                               int* __restrict__ ebase) {
    __shared__ int s[256];
    int t = threadIdx.x;
    int sum = 0;
    if (t < NCB)
        for (int b = 0; b < HISTB; b++) sum += hpart[b * NCB + t];
    s[t] = (t < NCB) ? sum : 0;
    __syncthreads();
    for (int off = 1; off < 256; off <<= 1) {
        int v = 0;
        if (t >= off) v = s[t - off];
        __syncthreads();
        s[t] += v;
        __syncthreads();
    }
    if (t == 0) ebase[0] = 0;
    if (t < NCB) ebase[t + 1] = s[t];
}

// ---------------- pass A: counting-sort edges into coarse buckets ----------------
__global__ __launch_bounds__(1024) void k_passA(const int* __restrict__ src, const int* __restrict__ dst,
                        const int* __restrict__ ebase, int* __restrict__ gfill,
                        unsigned* __restrict__ ebuf) {
    __shared__ unsigned lbuf[CHK];
    __shared__ unsigned char lbyte[CHK];
    __shared__ int hcnt[NCB];
    __shared__ int hbase[256];   // inclusive scan of hcnt
    __shared__ int goff[NCB];
    int t = threadIdx.x;
    if (t < NCB) hcnt[t] = 0;
    __syncthreads();
    int base = blockIdx.x * CHK;
    int cb[8], slot[8]; unsigned pk[8];
#pragma unroll
    for (int i = 0; i < 8; i++) {
        int e = base + i * 1024 + t;
        cb[i] = -1;
        if (e < NE) {
            int d = dst[e], s = src[e];
            cb[i] = d >> CBSH;
            pk[i] = ((unsigned)s << CBSH) | (unsigned)(d & 511);
            slot[i] = atomicAdd(&hcnt[cb[i]], 1);
        }
    }
    __syncthreads();
    if (t < 256) hbase[t] = (t < NCB) ? hcnt[t] : 0;
    __syncthreads();
    for (int off = 1; off < 256; off <<= 1) {
        int v = 0;
        if (t < 256 && t >= off) v = hbase[t - off];
        __syncthreads();
        if (t < 256) hbase[t] += v;
        __syncthreads();
    }
    if (t < NCB) {
        int c = hcnt[t];
        int g = c ? atomicAdd(&gfill[t], c) : 0;
        goff[t] = ebase[t] + g - (hbase[t] - c);
    }
    __syncthreads();
#pragma unroll
    for (int i = 0; i < 8; i++) {
        if (cb[i] >= 0) {
            int pos = hbase[cb[i]] - hcnt[cb[i]] + slot[i];
            lbuf[pos] = pk[i];
            lbyte[pos] = (unsigned char)cb[i];
        }
    }
    __syncthreads();
    int total = min(NE - base, CHK);
    for (int p = t; p < total; p += 1024) {
        unsigned v = lbuf[p];
        int b = lbyte[p];
        ebuf[goff[b] + p] = v;
    }
}

// ---------------- pass B: per-bucket node sort -> csr/degi/rowst/dis ----------------
__global__ __launch_bounds__(1024) void k_passB(const unsigned* __restrict__ ebuf, const int* __restrict__ ebase,
                        int* __restrict__ degi, int* __restrict__ rowst,
                        float* __restrict__ dis, int* __restrict__ csr) {
    __shared__ int cnt[512];
    __shared__ int nbase[512];
    __shared__ int fill[512];
    __shared__ int stage[MAXB];
    int t = threadIdx.x;
    int cb = blockIdx.x;
    int nb0 = cb << CBSH;
    int ncnt = min(512, NN - nb0);
    int e0 = ebase[cb], e1 = ebase[cb + 1];
    if (t < 512) { cnt[t] = 0; fill[t] = 0; }
    __syncthreads();
    for (int e = e0 + t; e < e1; e += 1024)
        atomicAdd(&cnt[ebuf[e] & 511], 1);
    __syncthreads();
    if (t < 512) nbase[t] = cnt[t];
    __syncthreads();
    for (int off = 1; off < 512; off <<= 1) {
        int v = 0;
        if (t < 512 && t >= off) v = nbase[t - off];
        __syncthreads();
        if (t < 512) nbase[t] += v;
        __syncthreads();
    }
    for (int e = e0 + t; e < e1; e += 1024) {
        unsigned v = ebuf[e];
        int local = v & 511;
        int s = atomicAdd(&fill[local], 1);
        stage[nbase[local] - cnt[local] + s] = (int)(v >> CBSH);
    }
    __syncthreads();
    int total = e1 - e0;
    for (int p = t; p < total; p += 1024) csr[e0 + p] = stage[p];
    if (t < ncnt) {
        int c = cnt[t];
        degi[nb0 + t] = c;
        rowst[nb0 + t] = e0 + nbase[t] - c;
        dis[nb0 + t] = rsqrtf((float)c + 1.0f);
    }
}

// ---------------- agg layer 1 (dis-WEIGHTED gather over unscaled table) ----------
// Identical memory structure to the proven k_agg (59.7 us floor); adds become
// fmas with the per-row dis[src] broadcast weight (+1 dword/row). Self term
// weighted by dis[n]; epilogue relu(dis[n]*a + b) unchanged.
__global__ __launch_bounds__(256) void k_agg_w(const unsigned short* __restrict__ ht, const int* __restrict__ rowst,
                      const int* __restrict__ degi, const int* __restrict__ csr,
                      const float* __restrict__ dis, const float* __restrict__ bias,
                      unsigned short* __restrict__ out) {
    int t = threadIdx.x;
    int grp = t >> 4;
    int q = t & 15;
    int n = blockIdx.x * 16 + grp;   // NN = 6250*16 exactly
    const uint4* base = (const uint4*)ht;

    float d = dis[n];
    uint4 sv = base[(size_t)n * 16 + q];
    float a[8];
    a[0] = d * bflo(sv.x); a[1] = d * bfhi(sv.x);
    a[2] = d * bflo(sv.y); a[3] = d * bfhi(sv.y);
    a[4] = d * bflo(sv.z); a[5] = d * bfhi(sv.z);
    a[6] = d * bflo(sv.w); a[7] = d * bfhi(sv.w);

    int start = rowst[n];
    int c = degi[n];
    int nb = c & ~7;
    int j = 0;
    for (; j < nb; j += 8) {
        int idx[8];
#pragma unroll
        for (int u = 0; u < 8; u++) idx[u] = csr[start + j + u];
        uint4 v[8]; float w[8];
#pragma unroll
        for (int u = 0; u < 8; u++) v[u] = base[(size_t)idx[u] * 16 + q];
#pragma unroll
        for (int u = 0; u < 8; u++) w[u] = dis[idx[u]];
#pragma unroll
        for (int u = 0; u < 8; u++) {
            a[0] = fmaf(w[u], bflo(v[u].x), a[0]); a[1] = fmaf(w[u], bfhi(v[u].x), a[1]);
            a[2] = fmaf(w[u], bflo(v[u].y), a[2]); a[3] = fmaf(w[u], bfhi(v[u].y), a[3]);
            a[4] = fmaf(w[u], bflo(v[u].z), a[4]); a[5] = fmaf(w[u], bfhi(v[u].z), a[5]);
            a[6] = fmaf(w[u], bflo(v[u].w), a[6]); a[7] = fmaf(w[u], bfhi(v[u].w), a[7]);
        }
    }
    if (j < c) {
        int idx[8];
#pragma unroll
        for (int u = 0; u < 8; u++) { int e = j + u; idx[u] = csr[start + (e < c ? e : c - 1)]; }
        uint4 v[8]; float w[8];
#pragma unroll
        for (int u = 0; u < 8; u++) v[u] = base[(size_t)idx[u] * 16 + q];
#pragma unroll
        for (int u = 0; u < 8; u++) w[u] = dis[idx[u]];
#pragma unroll
        for (int u = 0; u < 8; u++) {
            if (j + u < c) {
                a[0] = fmaf(w[u], bflo(v[u].x), a[0]); a[1] = fmaf(w[u], bfhi(v[u].x), a[1]);
                a[2] = fmaf(w[u], bflo(v[u].y), a[2]); a[3] = fmaf(w[u], bfhi(v[u].y), a[3]);
                a[4] = fmaf(w[u], bflo(v[u].z), a[4]); a[5] = fmaf(w[u], bfhi(v[u].z), a[5]);
                a[6] = fmaf(w[u], bflo(v[u].w), a[6]); a[7] = fmaf(w[u], bfhi(v[u].w), a[7]);
            }
        }
    }

    const float4* bp = (const float4*)bias;
    float4 b0 = bp[q * 2], b1 = bp[q * 2 + 1];
    uint4 o;
    {
        float ox = fmaxf(fmaf(d, a[0], b0.x), 0.f), oy = fmaxf(fmaf(d, a[1], b0.y), 0.f);
        o.x = ((unsigned)f2bf(oy) << 16) | (unsigned)f2bf(ox);
        ox = fmaxf(fmaf(d, a[2], b0.z), 0.f); oy = fmaxf(fmaf(d, a[3], b0.w), 0.f);
        o.y = ((unsigned)f2bf(oy) << 16) | (unsigned)f2bf(ox);
        ox = fmaxf(fmaf(d, a[4], b1.x), 0.f); oy = fmaxf(fmaf(d, a[5], b1.y), 0.f);
        o.z = ((unsigned)f2bf(oy) << 16) | (unsigned)f2bf(ox);
        ox = fmaxf(fmaf(d, a[6], b1.z), 0.f); oy = fmaxf(fmaf(d, a[7], b1.w), 0.f);
        o.w = ((unsigned)f2bf(oy) << 16) | (unsigned)f2bf(ox);
    }
    ((uint4*)out)[(size_t)n * 16 + q] = o;
}

// ---------------- MFMA GEMM layer 2: out = bf16((A @ W2) * dis), A bf16 ----------
__launch_bounds__(256, 2)
__global__ void k_gemm2(const unsigned short* __restrict__ Av,
                        const unsigned short* __restrict__ WT,
                        const float* __restrict__ dis,
                        unsigned short* __restrict__ out) {
    int tid = threadIdx.x;
    int wave = tid >> 6, lane = tid & 63;
    int quad = lane >> 4, l16 = lane & 15;

    int rbase = blockIdx.x * 128 + wave * 32;

    bf16x8 af[2][4];
#pragma unroll
    for (int s = 0; s < 2; s++) {
        int row = rbase + s * 16 + l16;
        if (row >= NN) row = NN - 1;
        const unsigned short* arow = Av + (size_t)row * CH + quad * 8;
#pragma unroll
        for (int ks = 0; ks < 4; ks++) af[s][ks] = *(const bf16x8*)(arow + ks * 32);
    }

    f32x4 acc[2][8];
#pragma unroll
    for (int s = 0; s < 2; s++)
#pragma unroll
        for (int t = 0; t < 8; t++) acc[s][t] = (f32x4){0.f, 0.f, 0.f, 0.f};

#pragma unroll
    for (int t = 0; t < 8; t++) {
        const unsigned short* wcol = WT + (size_t)(t * 16 + l16) * CH + quad * 8;
        bf16x8 b0 = *(const bf16x8*)(wcol);
        bf16x8 b1 = *(const bf16x8*)(wcol + 32);
        bf16x8 b2 = *(const bf16x8*)(wcol + 64);
        bf16x8 b3 = *(const bf16x8*)(wcol + 96);
#pragma unroll
        for (int s = 0; s < 2; s++) {
            acc[s][t] = __builtin_amdgcn_mfma_f32_16x16x32_bf16(af[s][0], b0, acc[s][t], 0, 0, 0);
            acc[s][t] = __builtin_amdgcn_mfma_f32_16x16x32_bf16(af[s][1], b1, acc[s][t], 0, 0, 0);
            acc[s][t] = __builtin_amdgcn_mfma_f32_16x16x32_bf16(af[s][2], b2, acc[s][t], 0, 0, 0);
            acc[s][t] = __builtin_amdgcn_mfma_f32_16x16x32_bf16(af[s][3], b3, acc[s][t], 0, 0, 0);
        }
    }

    // D layout per 16x16 tile: row = quad*4 + r, col = l16
#pragma unroll
    for (int s = 0; s < 2; s++) {
#pragma unroll
        for (int r = 0; r < 4; r++) {
            int orow = rbase + s * 16 + quad * 4 + r;
            if (orow < NN) {
                float d = dis[orow];
#pragma unroll
                for (int t = 0; t < 8; t++) {
                    out[(size_t)orow * CH + t * 16 + l16] = f2bf(acc[s][t][r] * d);
                }
            }
        }
    }
}

// ---------------- agg layer 2: proven kernel, verbatim (59.7 us floor) ----------
__global__ __launch_bounds__(256) void k_agg(const unsigned short* __restrict__ ht, const int* __restrict__ rowst,
                      const int* __restrict__ degi, const int* __restrict__ csr,
                      const float* __restrict__ dis, const float* __restrict__ bias,
                      unsigned short* __restrict__ out) {
    int t = threadIdx.x;
    int grp = t >> 4;
    int q = t & 15;
    int n = blockIdx.x * 16 + grp;
    const uint4* base = (const uint4*)ht;

    uint4 sv = base[(size_t)n * 16 + q];
    float a[8];
    a[0] = bflo(sv.x); a[1] = bfhi(sv.x);
    a[2] = bflo(sv.y); a[3] = bfhi(sv.y);
    a[4] = bflo(sv.z); a[5] = bfhi(sv.z);
    a[6] = bflo(sv.w); a[7] = bfhi(sv.w);

    int start = rowst[n];
    int c = degi[n];
    int nb = c & ~7;
    int j = 0;
    for (; j < nb; j += 8) {
        int idx[8];
#pragma unroll
        for (int u = 0; u < 8; u++) idx[u] = csr[start + j + u];
        uint4 v[8];
#pragma unroll
        for (int u = 0; u < 8; u++) v[u] = base[(size_t)idx[u] * 16 + q];
#pragma unroll
        for (int u = 0; u < 8; u++) {
            a[0] += bflo(v[u].x); a[1] += bfhi(v[u].x);
            a[2] += bflo(v[u].y); a[3] += bfhi(v[u].y);
            a[4] += bflo(v[u].z); a[5] += bfhi(v[u].z);
            a[6] += bflo(v[u].w); a[7] += bfhi(v[u].w);
        }
    }
    if (j < c) {
        int idx[8];
#pragma unroll
        for (int u = 0; u < 8; u++) { int e = j + u; idx[u] = csr[start + (e < c ? e : c - 1)]; }
        uint4 v[8];
#pragma unroll
        for (int u = 0; u < 8; u++) v[u] = base[(size_t)idx[u] * 16 + q];
#pragma unroll
        for (int u = 0; u < 8; u++) {
            if (j + u < c) {
                a[0] += bflo(v[u].x); a[1] += bfhi(v[u].x);
                a[2] += bflo(v[u].y); a[3] += bfhi(v[u].y);
                a[4] += bflo(v[u].z); a[5] += bfhi(v[u].z);
                a[6] += bflo(v[u].w); a[7] += bfhi(v[u].w);
            }
        }
    }

    float d = dis[n];
    const float4* bp = (const float4*)bias;
    float4 b0 = bp[q * 2], b1 = bp[q * 2 + 1];
    uint4 o;
    {
        float ox = fmaxf(fmaf(d, a[0], b0.x), 0.f), oy = fmaxf(fmaf(d, a[1], b0.y), 0.f);
        o.x = ((unsigned)f2bf(oy) << 16) | (unsigned)f2bf(ox);
        ox = fmaxf(fmaf(d, a[2], b0.z), 0.f); oy = fmaxf(fmaf(d, a[3], b0.w), 0.f);
        o.y = ((unsigned)f2bf(oy) << 16) | (unsigned)f2bf(ox);
        ox = fmaxf(fmaf(d, a[4], b1.x), 0.f); oy = fmaxf(fmaf(d, a[5], b1.y), 0.f);
        o.z = ((unsigned)f2bf(oy) << 16) | (unsigned)f2bf(ox);
        ox = fmaxf(fmaf(d, a[6], b1.z), 0.f); oy = fmaxf(fmaf(d, a[7], b1.w), 0.f);
        o.w = ((unsigned)f2bf(oy) << 16) | (unsigned)f2bf(ox);
    }
    ((uint4*)out)[(size_t)n * 16 + q] = o;
}

// ---------------- mean pool: 8 splits/graph, LDS reduce, few atomics ----------------
__global__ __launch_bounds__(512) void k_pool2(const unsigned short* __restrict__ h,
                                               const int* __restrict__ gptr,
                                               float* __restrict__ pooled) {
    int g = blockIdx.x >> 3;       // graph
    int s = blockIdx.x & 7;        // split
    int gs = gptr[g], ge = gptr[g + 1];
    int len = ge - gs;
    int i0 = gs + (int)(((long long)len * s) >> 3);
    int i1 = gs + (int)(((long long)len * (s + 1)) >> 3);
    int t = threadIdx.x;
    int pr = t & 63;               // channel pair 0..63
    int ro = t >> 6;               // row group 0..7
    const unsigned* base = (const unsigned*)h;
    float s0 = 0.f, s1 = 0.f;
    for (int n = i0 + ro; n < i1; n += 8) {
        unsigned v = base[(size_t)n * 64 + pr];
        s0 += bflo(v); s1 += bfhi(v);
    }
    __shared__ float red[2][8][64];
    red[0][ro][pr] = s0; red[1][ro][pr] = s1;
    __syncthreads();
    for (int off = 4; off >= 1; off >>= 1) {
        if (ro < off) {
            red[0][ro][pr] += red[0][ro + off][pr];
            red[1][ro][pr] += red[1][ro + off][pr];
        }
        __syncthreads();
    }
    if (ro == 0) {
        atomicAdd(&pooled[g * CH + pr * 2],     red[0][0][pr]);
        atomicAdd(&pooled[g * CH + pr * 2 + 1], red[1][0][pr]);
    }
}

// ---------------- final FC: out = (pooled/cnt) @ Wfc + bfc ----------------
__global__ void k_final(const float* __restrict__ pooled, const int* __restrict__ gptr,
                        const float* __restrict__ Wfc, const float* __restrict__ bfc,
                        float* __restrict__ out) {
    int idx = blockIdx.x * 256 + threadIdx.x;
    if (idx >= NG * OUTC) return;
    int g = idx >> 4, o = idx & 15;
    float c = (float)(gptr[g + 1] - gptr[g]);
    float inv = 1.0f / fmaxf(c, 1.0f);
    float s = 0.f;
    for (int k = 0; k < CH; k++) s += pooled[g * CH + k] * Wfc[k * OUTC + o];
    out[idx] = fmaf(s, inv, bfc[o]);
}

extern "C" void kernel_launch(void* const* d_in, const int* in_sizes, int n_in,
                              void* d_out, int out_size, void* d_ws, size_t ws_size,
                              hipStream_t stream) {
    (void)in_sizes; (void)n_in; (void)out_size; (void)ws_size;
    const float* x   = (const float*)d_in[0];
    const float* W1  = (const float*)d_in[1];
    const float* b1  = (const float*)d_in[2];
    const float* W2  = (const float*)d_in[3];
    const float* b2  = (const float*)d_in[4];
    const float* Wfc = (const float*)d_in[5];
    const float* bfc = (const float*)d_in[6];
    const int* ei    = (const int*)d_in[7];
    const int* batch = (const int*)d_in[8];
    const int* esrc = ei;
    const int* edst = ei + NE;
    float* out = (float*)d_out;

    char* w = (char*)d_ws;
    unsigned short* bufA = (unsigned short*)w; w += (size_t)NN * CH * 2;
    unsigned short* bufB = (unsigned short*)w; w += (size_t)NN * CH * 2;
    unsigned short* wt2  = (unsigned short*)w; w += (size_t)CH * CH * 2;
    unsigned* ebuf = (unsigned*)w; w += (size_t)NE * 4;
    int* csr    = (int*)w;    w += (size_t)NE * 4;
    int* degi   = (int*)w;    w += (size_t)NN * 4;
    int* rowst  = (int*)w;    w += (size_t)NN * 4;
    float* dis  = (float*)w;  w += (size_t)NN * 4;
    int* hpart  = (int*)w;    w += (size_t)HISTB * NCB * 4;
    int* ebase  = (int*)w;    w += (NCB + 1) * 4;
    int* gfill  = (int*)w;    w += NCB * 4;
    int* gptr   = (int*)w;    w += (NG + 1) * 4;
    float* pooled = (float*)w; w += (size_t)NG * CH * 4;

    const int fusedBlocks = GEMMB + HISTB + PREPB;   // 1369
    const int gemmBlocks = (NN + 127) / 128;         // 782
    const int aggBlocks  = NN / 16;                  // 6250

    // fused: gemm1 (unscaled) | hist | prep — all independent
    k_fused0<<<fusedBlocks, 256, 0, stream>>>(x, W1, W2, wt2, batch, gptr, gfill,
                                              pooled, edst, hpart, bufA);
    k_bscan<<<1, 256, 0, stream>>>(hpart, ebase);
    k_passA<<<HISTB, 1024, 0, stream>>>(esrc, edst, ebase, gfill, ebuf);
    k_passB<<<NCB, 1024, 0, stream>>>(ebuf, ebase, degi, rowst, dis, csr);

    // layer 1 aggregation (dis-weighted gather over unscaled bufA)
    k_agg_w<<<aggBlocks, 256, 0, stream>>>(bufA, rowst, degi, csr, dis, b1, bufB);
    // layer 2 (bf16 input, dis-scaled output)
    k_gemm2<<<gemmBlocks, 256, 0, stream>>>(bufB, wt2, dis, bufA);
    k_agg<<<aggBlocks, 256, 0, stream>>>(bufA, rowst, degi, csr, dis, b2, bufB);

    k_pool2<<<NG * PS, 512, 0, stream>>>(bufB, gptr, pooled);
    k_final<<<(NG * OUTC + 255) / 256, 256, 0, stream>>>(pooled, gptr, Wfc, bfc, out);
}

// Round 8
// 312.215 us; speedup vs baseline: 1.5317x; 1.0048x over previous
//
#include <hip/hip_runtime.h>
#include <math.h>

#define NN 100000
#define NE 1600000
#define CH 128
#define OUTC 16
#define NG 64

#define CBSH 8                      // 256 nodes per coarse bucket
#define NCB 391                     // ceil(NN / 256)
#define CHK 4096                    // edges per passA block  (391 blocks)
#define HCHK 8192                   // edges per hist block   (196 blocks)
#define HISTB 196
#define PREPB 391
#define MAXB 6144                   // csr staging cap per bucket (avg 4092, +32 sigma)
#define PS 8                        // pool splits per graph
#define LDA 136                     // LDS W-tile row stride in ushorts (272 B)

typedef __attribute__((ext_vector_type(8))) short bf16x8;
typedef __attribute__((ext_vector_type(4))) float f32x4;

__device__ __forceinline__ unsigned short f2bf(float f) {
    union { float f; unsigned u; } v; v.f = f;
    unsigned r = v.u + 0x7FFF + ((v.u >> 16) & 1);   // RNE
    return (unsigned short)(r >> 16);
}
__device__ __forceinline__ float bflo(unsigned u) {
    union { unsigned u; float f; } v; v.u = u << 16; return v.f;
}
__device__ __forceinline__ float bfhi(unsigned u) {
    union { unsigned u; float f; } v; v.u = u & 0xffff0000u; return v.f;
}

// ---------------- fused0: hist (global-atomic bcnt) | prep ----------------
// bcnt pre-zeroed by hipMemsetAsync; hist blocks accumulate per-block LDS
// histograms then flush atomically (R1-proven). prep casts W2, builds gptr,
// zeroes gfill/pooled. Branches disjoint, no shared data.
__global__ __launch_bounds__(256) void k_fused0(const int* __restrict__ edst, int* __restrict__ bcnt,
                         const float* __restrict__ W2, unsigned short* __restrict__ wt2,
                         const int* __restrict__ batch, int* __restrict__ gptr,
                         int* __restrict__ gfill, float* __restrict__ pooled) {
    int b = blockIdx.x;
    int t = threadIdx.x;
    if (b < HISTB) {
        __shared__ int h[NCB];
        for (int i = t; i < NCB; i += 256) h[i] = 0;
        __syncthreads();
        int base = b * HCHK;
#pragma unroll
        for (int i = 0; i < 32; i++) {
            int e = base + i * 256 + t;
            if (e < NE) atomicAdd(&h[edst[e] >> CBSH], 1);
        }
        __syncthreads();
        for (int i = t; i < NCB; i += 256)
            if (h[i]) atomicAdd(&bcnt[i], h[i]);
    } else {
        int i = (b - HISTB) * 256 + t;
        if (i < CH * CH) {
            int k = i >> 7, n = i & 127;
            wt2[n * CH + k] = f2bf(W2[i]);
        }
        if (i < NCB) gfill[i] = 0;
        if (i < NG * CH) pooled[i] = 0.f;
        if (i < NN) {
            int bb = batch[i];
            int prev = (i == 0) ? -1 : batch[i - 1];
            for (int g = prev + 1; g <= bb; g++) gptr[g] = i;
            if (i == NN - 1) {
                for (int g = bb + 1; g <= NG; g++) gptr[g] = NN;
            }
        }
    }
}

// ---------------- pass A: counting-sort edges into 391 coarse buckets ----------
// 512 threads, 4096 edges/block. Bucket-base scan folded in-block (eb[] rides
// the hbase scan rounds — R4-R6 proven); block 0 publishes ebase for passB.
__global__ __launch_bounds__(512) void k_passA(const int* __restrict__ src, const int* __restrict__ dst,
                        const int* __restrict__ bcnt, int* __restrict__ gfill,
                        unsigned* __restrict__ ebuf, int* __restrict__ ebase) {
    __shared__ unsigned lbuf[CHK];
    __shared__ unsigned short lbkt[CHK];
    __shared__ int hcnt[NCB];
    __shared__ int hbase[512];   // inclusive scan of hcnt
    __shared__ int eb[512];      // inclusive scan of bcnt
    __shared__ int goff[NCB];
    int t = threadIdx.x;
    for (int i = t; i < NCB; i += 512) hcnt[i] = 0;
    eb[t] = (t < NCB) ? bcnt[t] : 0;
    __syncthreads();
    int base = blockIdx.x * CHK;
    int cb[8], slot[8]; unsigned pk[8];
#pragma unroll
    for (int i = 0; i < 8; i++) {
        int e = base + i * 512 + t;
        cb[i] = -1;
        if (e < NE) {
            int d = dst[e], s = src[e];
            cb[i] = d >> CBSH;
            pk[i] = ((unsigned)s << CBSH) | (unsigned)(d & 255);
            slot[i] = atomicAdd(&hcnt[cb[i]], 1);
        }
    }
    __syncthreads();
    hbase[t] = (t < NCB) ? hcnt[t] : 0;
    __syncthreads();
    for (int off = 1; off < 512; off <<= 1) {
        int v1 = 0, v2 = 0;
        if (t >= off) { v1 = hbase[t - off]; v2 = eb[t - off]; }
        __syncthreads();
        if (t >= off) { hbase[t] += v1; eb[t] += v2; }
        __syncthreads();
    }
    if (t < NCB) {
        int c = hcnt[t];
        int g = c ? atomicAdd(&gfill[t], c) : 0;
        int eb_ex = t ? eb[t - 1] : 0;
        goff[t] = eb_ex + g - (hbase[t] - c);
    }
    if (blockIdx.x == 0) {
        if (t == 0) ebase[0] = 0;
        if (t < NCB) ebase[t + 1] = eb[t];
    }
    __syncthreads();
#pragma unroll
    for (int i = 0; i < 8; i++) {
        if (cb[i] >= 0) {
            int pos = hbase[cb[i]] - hcnt[cb[i]] + slot[i];
            lbuf[pos] = pk[i];
            lbkt[pos] = (unsigned short)cb[i];
        }
    }
    __syncthreads();
    int total = min(NE - base, CHK);
    for (int p = t; p < total; p += 512) {
        unsigned v = lbuf[p];
        int bk = lbkt[p];
        ebuf[goff[bk] + p] = v;
    }
}

// ---------------- fusedB: passB (391 blocks) | gemm1 (782 blocks) ----------------
// passB: per-bucket (256 nodes) sort -> csr/degi/rowst/dis, reads ebase.
// gemm1: bf16((x @ W1)) UNSCALED (agg_w applies dis weights), self-staged W1^T.
// Disjoint branches share one 34.8 KB LDS buffer.
__launch_bounds__(256, 2)
__global__ void k_fusedB(const unsigned* __restrict__ ebuf, const int* __restrict__ ebase,
                         int* __restrict__ degi, int* __restrict__ rowst,
                         float* __restrict__ dis, int* __restrict__ csr,
                         const float* __restrict__ x, const float* __restrict__ W1,
                         unsigned short* __restrict__ bufA) {
    __shared__ __align__(16) unsigned short smem[128 * LDA];   // 34816 B
    int b = blockIdx.x;
    int t = threadIdx.x;

    if (b < NCB) {
        // ---- passB ----
        int* cnt   = (int*)smem;
        int* nbase = cnt + 256;
        int* fill  = nbase + 256;
        int* stage = fill + 256;          // MAXB ints => total 27.6 KB
        int cb = b;
        int nb0 = cb << CBSH;
        int ncnt = min(256, NN - nb0);
        int e0 = ebase[cb], e1 = ebase[cb + 1];
        cnt[t] = 0; fill[t] = 0;
        __syncthreads();
        for (int e = e0 + t; e < e1; e += 256)
            atomicAdd(&cnt[ebuf[e] & 255], 1);
        __syncthreads();
        nbase[t] = cnt[t];
        __syncthreads();
        for (int off = 1; off < 256; off <<= 1) {
            int v = 0;
            if (t >= off) v = nbase[t - off];
            __syncthreads();
            if (t >= off) nbase[t] += v;
            __syncthreads();
        }
        for (int e = e0 + t; e < e1; e += 256) {
            unsigned v = ebuf[e];
            int local = v & 255;
            int s = atomicAdd(&fill[local], 1);
            stage[nbase[local] - cnt[local] + s] = (int)(v >> CBSH);
        }
        __syncthreads();
        int total = e1 - e0;
        for (int p = t; p < total; p += 256) csr[e0 + p] = stage[p];
        if (t < ncnt) {
            int c = cnt[t];
            degi[nb0 + t] = c;
            rowst[nb0 + t] = e0 + nbase[t] - c;
            dis[nb0 + t] = rsqrtf((float)c + 1.0f);
        }
    } else {
        // ---- gemm1 (R7-proven branch) ----
        unsigned short* wlds = smem;
#pragma unroll
        for (int it = 0; it < 64; it++) {
            int i = it * 256 + t;                 // i = k*128 + n
            int k = i >> 7, n = i & 127;
            wlds[n * LDA + k] = f2bf(W1[i]);
        }
        __syncthreads();

        int wave = t >> 6, lane = t & 63;
        int quad = lane >> 4, l16 = lane & 15;
        int rbase = (b - NCB) * 128 + wave * 32;

        bf16x8 af[2][4];
#pragma unroll
        for (int s = 0; s < 2; s++) {
            int row = rbase + s * 16 + l16;
            if (row >= NN) row = NN - 1;
            const float* arow = x + (size_t)row * CH + quad * 8;
#pragma unroll
            for (int ks = 0; ks < 4; ks++) {
                float4 lo = *(const float4*)(arow + ks * 32);
                float4 hi = *(const float4*)(arow + ks * 32 + 4);
                union { bf16x8 v; unsigned short u[8]; } tmp;
                tmp.u[0] = f2bf(lo.x); tmp.u[1] = f2bf(lo.y);
                tmp.u[2] = f2bf(lo.z); tmp.u[3] = f2bf(lo.w);
                tmp.u[4] = f2bf(hi.x); tmp.u[5] = f2bf(hi.y);
                tmp.u[6] = f2bf(hi.z); tmp.u[7] = f2bf(hi.w);
                af[s][ks] = tmp.v;
            }
        }

        f32x4 acc[2][8];
#pragma unroll
        for (int s = 0; s < 2; s++)
#pragma unroll
            for (int tt = 0; tt < 8; tt++) acc[s][tt] = (f32x4){0.f, 0.f, 0.f, 0.f};

#pragma unroll
        for (int tt = 0; tt < 8; tt++) {
            const unsigned short* wcol = &wlds[(tt * 16 + l16) * LDA + quad * 8];
            bf16x8 b0 = *(const bf16x8*)(wcol);
            bf16x8 b1 = *(const bf16x8*)(wcol + 32);
            bf16x8 b2 = *(const bf16x8*)(wcol + 64);
            bf16x8 b3 = *(const bf16x8*)(wcol + 96);
#pragma unroll
            for (int s = 0; s < 2; s++) {
                acc[s][tt] = __builtin_amdgcn_mfma_f32_16x16x32_bf16(af[s][0], b0, acc[s][tt], 0, 0, 0);
                acc[s][tt] = __builtin_amdgcn_mfma_f32_16x16x32_bf16(af[s][1], b1, acc[s][tt], 0, 0, 0);
                acc[s][tt] = __builtin_amdgcn_mfma_f32_16x16x32_bf16(af[s][2], b2, acc[s][tt], 0, 0, 0);
                acc[s][tt] = __builtin_amdgcn_mfma_f32_16x16x32_bf16(af[s][3], b3, acc[s][tt], 0, 0, 0);
            }
        }

        // D layout per 16x16 tile: row = quad*4 + r, col = l16
#pragma unroll
        for (int s = 0; s < 2; s++) {
#pragma unroll
            for (int r = 0; r < 4; r++) {
                int orow = rbase + s * 16 + quad * 4 + r;
                if (orow < NN) {
#pragma unroll
                    for (int tt = 0; tt < 8; tt++)
                        bufA[(size_t)orow * CH + tt * 16 + l16] = f2bf(acc[s][tt][r]);
                }
            }
        }
    }
}

// ---------------- agg layer 1 (dis-WEIGHTED gather over unscaled table) ----------
// Proven R7 kernel, verbatim (62.3 us).
__global__ __launch_bounds__(256) void k_agg_w(const unsigned short* __restrict__ ht, const int* __restrict__ rowst,
                      const int* __restrict__ degi, const int* __restrict__ csr,
                      const float* __restrict__ dis, const float* __restrict__ bias,
                      unsigned short* __restrict__ out) {
    int t = threadIdx.x;
    int grp = t >> 4;
    int q = t & 15;
    int n = blockIdx.x * 16 + grp;   // NN = 6250*16 exactly
    const uint4* base = (const uint4*)ht;

    float d = dis[n];
    uint4 sv = base[(size_t)n * 16 + q];
    float a[8];
    a[0] = d * bflo(sv.x); a[1] = d * bfhi(sv.x);
    a[2] = d * bflo(sv.y); a[3] = d * bfhi(sv.y);
    a[4] = d * bflo(sv.z); a[5] = d * bfhi(sv.z);
    a[6] = d * bflo(sv.w); a[7] = d * bfhi(sv.w);

    int start = rowst[n];
    int c = degi[n];
    int nb = c & ~7;
    int j = 0;
    for (; j < nb; j += 8) {
        int idx[8];
#pragma unroll
        for (int u = 0; u < 8; u++) idx[u] = csr[start + j + u];
        uint4 v[8]; float w[8];
#pragma unroll
        for (int u = 0; u < 8; u++) v[u] = base[(size_t)idx[u] * 16 + q];
#pragma unroll
        for (int u = 0; u < 8; u++) w[u] = dis[idx[u]];
#pragma unroll
        for (int u = 0; u < 8; u++) {
            a[0] = fmaf(w[u], bflo(v[u].x), a[0]); a[1] = fmaf(w[u], bfhi(v[u].x), a[1]);
            a[2] = fmaf(w[u], bflo(v[u].y), a[2]); a[3] = fmaf(w[u], bfhi(v[u].y), a[3]);
            a[4] = fmaf(w[u], bflo(v[u].z), a[4]); a[5] = fmaf(w[u], bfhi(v[u].z), a[5]);
            a[6] = fmaf(w[u], bflo(v[u].w), a[6]); a[7] = fmaf(w[u], bfhi(v[u].w), a[7]);
        }
    }
    if (j < c) {
        int idx[8];
#pragma unroll
        for (int u = 0; u < 8; u++) { int e = j + u; idx[u] = csr[start + (e < c ? e : c - 1)]; }
        uint4 v[8]; float w[8];
#pragma unroll
        for (int u = 0; u < 8; u++) v[u] = base[(size_t)idx[u] * 16 + q];
#pragma unroll
        for (int u = 0; u < 8; u++) w[u] = dis[idx[u]];
#pragma unroll
        for (int u = 0; u < 8; u++) {
            if (j + u < c) {
                a[0] = fmaf(w[u], bflo(v[u].x), a[0]); a[1] = fmaf(w[u], bfhi(v[u].x), a[1]);
                a[2] = fmaf(w[u], bflo(v[u].y), a[2]); a[3] = fmaf(w[u], bfhi(v[u].y), a[3]);
                a[4] = fmaf(w[u], bflo(v[u].z), a[4]); a[5] = fmaf(w[u], bfhi(v[u].z), a[5]);
                a[6] = fmaf(w[u], bflo(v[u].w), a[6]); a[7] = fmaf(w[u], bfhi(v[u].w), a[7]);
            }
        }
    }

    const float4* bp = (const float4*)bias;
    float4 b0 = bp[q * 2], b1 = bp[q * 2 + 1];
    uint4 o;
    {
        float ox = fmaxf(fmaf(d, a[0], b0.x), 0.f), oy = fmaxf(fmaf(d, a[1], b0.y), 0.f);
        o.x = ((unsigned)f2bf(oy) << 16) | (unsigned)f2bf(ox);
        ox = fmaxf(fmaf(d, a[2], b0.z), 0.f); oy = fmaxf(fmaf(d, a[3], b0.w), 0.f);
        o.y = ((unsigned)f2bf(oy) << 16) | (unsigned)f2bf(ox);
        ox = fmaxf(fmaf(d, a[4], b1.x), 0.f); oy = fmaxf(fmaf(d, a[5], b1.y), 0.f);
        o.z = ((unsigned)f2bf(oy) << 16) | (unsigned)f2bf(ox);
        ox = fmaxf(fmaf(d, a[6], b1.z), 0.f); oy = fmaxf(fmaf(d, a[7], b1.w), 0.f);
        o.w = ((unsigned)f2bf(oy) << 16) | (unsigned)f2bf(ox);
    }
    ((uint4*)out)[(size_t)n * 16 + q] = o;
}

// ---------------- MFMA GEMM layer 2: out = bf16((A @ W2) * dis), A bf16 ----------
__launch_bounds__(256, 2)
__global__ void k_gemm2(const unsigned short* __restrict__ Av,
                        const unsigned short* __restrict__ WT,
                        const float* __restrict__ dis,
                        unsigned short* __restrict__ out) {
    int tid = threadIdx.x;
    int wave = tid >> 6, lane = tid & 63;
    int quad = lane >> 4, l16 = lane & 15;

    int rbase = blockIdx.x * 128 + wave * 32;

    bf16x8 af[2][4];
#pragma unroll
    for (int s = 0; s < 2; s++) {
        int row = rbase + s * 16 + l16;
        if (row >= NN) row = NN - 1;
        const unsigned short* arow = Av + (size_t)row * CH + quad * 8;
#pragma unroll
        for (int ks = 0; ks < 4; ks++) af[s][ks] = *(const bf16x8*)(arow + ks * 32);
    }

    f32x4 acc[2][8];
#pragma unroll
    for (int s = 0; s < 2; s++)
#pragma unroll
        for (int t = 0; t < 8; t++) acc[s][t] = (f32x4){0.f, 0.f, 0.f, 0.f};

#pragma unroll
    for (int t = 0; t < 8; t++) {
        const unsigned short* wcol = WT + (size_t)(t * 16 + l16) * CH + quad * 8;
        bf16x8 b0 = *(const bf16x8*)(wcol);
        bf16x8 b1 = *(const bf16x8*)(wcol + 32);
        bf16x8 b2 = *(const bf16x8*)(wcol + 64);
        bf16x8 b3 = *(const bf16x8*)(wcol + 96);
#pragma unroll
        for (int s = 0; s < 2; s++) {
            acc[s][t] = __builtin_amdgcn_mfma_f32_16x16x32_bf16(af[s][0], b0, acc[s][t], 0, 0, 0);
            acc[s][t] = __builtin_amdgcn_mfma_f32_16x16x32_bf16(af[s][1], b1, acc[s][t], 0, 0, 0);
            acc[s][t] = __builtin_amdgcn_mfma_f32_16x16x32_bf16(af[s][2], b2, acc[s][t], 0, 0, 0);
            acc[s][t] = __builtin_amdgcn_mfma_f32_16x16x32_bf16(af[s][3], b3, acc[s][t], 0, 0, 0);
        }
    }

    // D layout per 16x16 tile: row = quad*4 + r, col = l16
#pragma unroll
    for (int s = 0; s < 2; s++) {
#pragma unroll
        for (int r = 0; r < 4; r++) {
            int orow = rbase + s * 16 + quad * 4 + r;
            if (orow < NN) {
                float d = dis[orow];
#pragma unroll
                for (int t = 0; t < 8; t++) {
                    out[(size_t)orow * CH + t * 16 + l16] = f2bf(acc[s][t][r] * d);
                }
            }
        }
    }
}

// ---------------- agg layer 2: proven kernel, verbatim (59.7 us floor) ----------
__global__ __launch_bounds__(256) void k_agg(const unsigned short* __restrict__ ht, const int* __restrict__ rowst,
                      const int* __restrict__ degi, const int* __restrict__ csr,
                      const float* __restrict__ dis, const float* __restrict__ bias,
                      unsigned short* __restrict__ out) {
    int t = threadIdx.x;
    int grp = t >> 4;
    int q = t & 15;
    int n = blockIdx.x * 16 + grp;
    const uint4* base = (const uint4*)ht;

    uint4 sv = base[(size_t)n * 16 + q];
    float a[8];
    a[0] = bflo(sv.x); a[1] = bfhi(sv.x);
    a[2] = bflo(sv.y); a[3] = bfhi(sv.y);
    a[4] = bflo(sv.z); a[5] = bfhi(sv.z);
    a[6] = bflo(sv.w); a[7] = bfhi(sv.w);

    int start = rowst[n];
    int c = degi[n];
    int nb = c & ~7;
    int j = 0;
    for (; j < nb; j += 8) {
        int idx[8];
#pragma unroll
        for (int u = 0; u < 8; u++) idx[u] = csr[start + j + u];
        uint4 v[8];
#pragma unroll
        for (int u = 0; u < 8; u++) v[u] = base[(size_t)idx[u] * 16 + q];
#pragma unroll
        for (int u = 0; u < 8; u++) {
            a[0] += bflo(v[u].x); a[1] += bfhi(v[u].x);
            a[2] += bflo(v[u].y); a[3] += bfhi(v[u].y);
            a[4] += bflo(v[u].z); a[5] += bfhi(v[u].z);
            a[6] += bflo(v[u].w); a[7] += bfhi(v[u].w);
        }
    }
    if (j < c) {
        int idx[8];
#pragma unroll
        for (int u = 0; u < 8; u++) { int e = j + u; idx[u] = csr[start + (e < c ? e : c - 1)]; }
        uint4 v[8];
#pragma unroll
        for (int u = 0; u < 8; u++) v[u] = base[(size_t)idx[u] * 16 + q];
#pragma unroll
        for (int u = 0; u < 8; u++) {
            if (j + u < c) {
                a[0] += bflo(v[u].x); a[1] += bfhi(v[u].x);
                a[2] += bflo(v[u].y); a[3] += bfhi(v[u].y);
                a[4] += bflo(v[u].z); a[5] += bfhi(v[u].z);
                a[6] += bflo(v[u].w); a[7] += bfhi(v[u].w);
            }
        }
    }

    float d = dis[n];
    const float4* bp = (const float4*)bias;
    float4 b0 = bp[q * 2], b1 = bp[q * 2 + 1];
    uint4 o;
    {
        float ox = fmaxf(fmaf(d, a[0], b0.x), 0.f), oy = fmaxf(fmaf(d, a[1], b0.y), 0.f);
        o.x = ((unsigned)f2bf(oy) << 16) | (unsigned)f2bf(ox);
        ox = fmaxf(fmaf(d, a[2], b0.z), 0.f); oy = fmaxf(fmaf(d, a[3], b0.w), 0.f);
        o.y = ((unsigned)f2bf(oy) << 16) | (unsigned)f2bf(ox);
        ox = fmaxf(fmaf(d, a[4], b1.x), 0.f); oy = fmaxf(fmaf(d, a[5], b1.y), 0.f);
        o.z = ((unsigned)f2bf(oy) << 16) | (unsigned)f2bf(ox);
        ox = fmaxf(fmaf(d, a[6], b1.z), 0.f); oy = fmaxf(fmaf(d, a[7], b1.w), 0.f);
        o.w = ((unsigned)f2bf(oy) << 16) | (unsigned)f2bf(ox);
    }
    ((uint4*)out)[(size_t)n * 16 + q] = o;
}

// ---------------- mean pool: 8 splits/graph, LDS reduce, few atomics ----------------
__global__ __launch_bounds__(512) void k_pool2(const unsigned short* __restrict__ h,
                                               const int* __restrict__ gptr,
                                               float* __restrict__ pooled) {
    int g = blockIdx.x >> 3;       // graph
    int s = blockIdx.x & 7;        // split
    int gs = gptr[g], ge = gptr[g + 1];
    int len = ge - gs;
    int i0 = gs + (int)(((long long)len * s) >> 3);
    int i1 = gs + (int)(((long long)len * (s + 1)) >> 3);
    int t = threadIdx.x;
    int pr = t & 63;               // channel pair 0..63
    int ro = t >> 6;               // row group 0..7
    const unsigned* base = (const unsigned*)h;
    float s0 = 0.f, s1 = 0.f;
    for (int n = i0 + ro; n < i1; n += 8) {
        unsigned v = base[(size_t)n * 64 + pr];
        s0 += bflo(v); s1 += bfhi(v);
    }
    __shared__ float red[2][8][64];
    red[0][ro][pr] = s0; red[1][ro][pr] = s1;
    __syncthreads();
    for (int off = 4; off >= 1; off >>= 1) {
        if (ro < off) {
            red[0][ro][pr] += red[0][ro + off][pr];
            red[1][ro][pr] += red[1][ro + off][pr];
        }
        __syncthreads();
    }
    if (ro == 0) {
        atomicAdd(&pooled[g * CH + pr * 2],     red[0][0][pr]);
        atomicAdd(&pooled[g * CH + pr * 2 + 1], red[1][0][pr]);
    }
}

// ---------------- final FC: out = (pooled/cnt) @ Wfc + bfc ----------------
__global__ void k_final(const float* __restrict__ pooled, const int* __restrict__ gptr,
                        const float* __restrict__ Wfc, const float* __restrict__ bfc,
                        float* __restrict__ out) {
    int idx = blockIdx.x * 256 + threadIdx.x;
    if (idx >= NG * OUTC) return;
    int g = idx >> 4, o = idx & 15;
    float c = (float)(gptr[g + 1] - gptr[g]);
    float inv = 1.0f / fmaxf(c, 1.0f);
    float s = 0.f;
    for (int k = 0; k < CH; k++) s += pooled[g * CH + k] * Wfc[k * OUTC + o];
    out[idx] = fmaf(s, inv, bfc[o]);
}

extern "C" void kernel_launch(void* const* d_in, const int* in_sizes, int n_in,
                              void* d_out, int out_size, void* d_ws, size_t ws_size,
                              hipStream_t stream) {
    (void)in_sizes; (void)n_in; (void)out_size; (void)ws_size;
    const float* x   = (const float*)d_in[0];
    const float* W1  = (const float*)d_in[1];
    const float* b1  = (const float*)d_in[2];
    const float* W2  = (const float*)d_in[3];
    const float* b2  = (const float*)d_in[4];
    const float* Wfc = (const float*)d_in[5];
    const float* bfc = (const float*)d_in[6];
    const int* ei    = (const int*)d_in[7];
    const int* batch = (const int*)d_in[8];
    const int* esrc = ei;
    const int* edst = ei + NE;
    float* out = (float*)d_out;

    char* w = (char*)d_ws;
    unsigned short* bufA = (unsigned short*)w; w += (size_t)NN * CH * 2;
    unsigned short* bufB = (unsigned short*)w; w += (size_t)NN * CH * 2;
    unsigned short* wt2  = (unsigned short*)w; w += (size_t)CH * CH * 2;
    unsigned* ebuf = (unsigned*)w; w += (size_t)NE * 4;
    int* csr    = (int*)w;    w += (size_t)NE * 4;
    int* degi   = (int*)w;    w += (size_t)NN * 4;
    int* rowst  = (int*)w;    w += (size_t)NN * 4;
    float* dis  = (float*)w;  w += (size_t)NN * 4;
    int* bcnt   = (int*)w;    w += NCB * 4;
    int* ebase  = (int*)w;    w += (NCB + 1) * 4;
    int* gfill  = (int*)w;    w += NCB * 4;
    int* gptr   = (int*)w;    w += (NG + 1) * 4;
    float* pooled = (float*)w; w += (size_t)NG * CH * 4;

    const int gemmBlocks = (NN + 127) / 128;         // 782
    const int aggBlocks  = NN / 16;                  // 6250
    const int passABlocks = (NE + CHK - 1) / CHK;    // 391

    hipMemsetAsync(bcnt, 0, NCB * sizeof(int), stream);

    // fused: hist (global-atomic bcnt) | prep
    k_fused0<<<HISTB + PREPB, 256, 0, stream>>>(edst, bcnt, W2, wt2, batch, gptr, gfill, pooled);
    // counting-sort pass A (391 blocks, folded bucket-base scan; block 0 -> ebase)
    k_passA<<<passABlocks, 512, 0, stream>>>(esrc, edst, bcnt, gfill, ebuf, ebase);
    // fused: passB (391 blocks) | gemm1 (782 blocks, unscaled output)
    k_fusedB<<<NCB + gemmBlocks, 256, 0, stream>>>(ebuf, ebase, degi, rowst, dis, csr, x, W1, bufA);

    // layer 1 aggregation (dis-weighted gather over unscaled bufA)
    k_agg_w<<<aggBlocks, 256, 0, stream>>>(bufA, rowst, degi, csr, dis, b1, bufB);
    // layer 2 (bf16 input, dis-scaled output)
    k_gemm2<<<gemmBlocks, 256, 0, stream>>>(bufB, wt2, dis, bufA);
    k_agg<<<aggBlocks, 256, 0, stream>>>(bufA, rowst, degi, csr, dis, b2, bufB);

    k_pool2<<<NG * PS, 512, 0, stream>>>(bufB, gptr, pooled);
    k_final<<<(NG * OUTC + 255) / 256, 256, 0, stream>>>(pooled, gptr, Wfc, bfc, out);
}